// Round 1
// baseline (3458.599 us; speedup 1.0000x reference)
//
#include <hip/hip_runtime.h>
#include <math.h>

// Workspace layout (float offsets)
#define WS_XIN   0L          // [512][128]
#define WS_GF    65536L      // [512][1024]
#define WS_FS    589824L     // [512][256]
#define WS_XO    720896L     // [512][256]
#define WS_GX    851968L     // [512][1024]
#define WS_Q     1376256L    // [512][65536]
#define WS_WVE   34930688L   // [256][256]
#define WS_BVE   34996224L   // [256]
#define WS_KT    34996480L   // [8][65536]  (Kt[b][d*256+g])
#define WS_H     35520768L   // [8][256]
#define WS_C     35522816L   // [8][256]
#define WS_OG    35524864L   // [8][256]
#define WS_VW    35526912L   // [8][256]
// total 35528960 floats = 142.1 MB

__device__ __forceinline__ float sigmf(float x){ return 1.0f/(1.0f + expf(-x)); }

// ---------------- init: zero h,c and build xin[r][m] = x[b][m][t], r = t*8+b
__launch_bounds__(256)
__global__ void k_init(const float* __restrict__ x, float* __restrict__ ws){
  int i = blockIdx.x*256 + threadIdx.x;   // 65536 threads
  int r = i >> 7, m = i & 127;
  int t = r >> 3, b = r & 7;
  ws[WS_XIN + i] = x[b*8192 + m*64 + t];
  if (i < 2048){ ws[WS_H + i] = 0.f; ws[WS_C + i] = 0.f; }
}

// ---------------- generic GEMM: out[n][m] = act( sum_k W[m][k]*X[n][k] + b1[m] (+b2[m]) )
// tiles: 128m x 128n, k-tile 64. grid.x = M/128, grid.y = N/128. act: 0 none, 1 relu, 2 sigmoid
__launch_bounds__(256)
__global__ void k_gemm_nt(const float* __restrict__ W, const float* __restrict__ X,
                          const float* __restrict__ b1, const float* __restrict__ b2,
                          float* __restrict__ out, int M, int K, int act){
  __shared__ float Wt[64*132];
  __shared__ float Xt[64*132];
  const int tid = threadIdx.x;
  const int tx = tid & 15, ty = tid >> 4;
  const int m0 = blockIdx.x * 128, n0 = blockIdx.y * 128;
  float acc[8][8];
  #pragma unroll
  for (int i = 0; i < 8; i++)
    #pragma unroll
    for (int j = 0; j < 8; j++) acc[i][j] = 0.f;

  for (int k0 = 0; k0 < K; k0 += 64){
    #pragma unroll
    for (int i = 0; i < 8; i++){
      int f4 = i*256 + tid;
      int row = f4 >> 4;
      int j4 = (tid & 15) * 4;
      float4 w = *(const float4*)&W[(size_t)(m0+row)*K + k0 + j4];
      Wt[(j4+0)*132 + row] = w.x;
      Wt[(j4+1)*132 + row] = w.y;
      Wt[(j4+2)*132 + row] = w.z;
      Wt[(j4+3)*132 + row] = w.w;
      float4 xv = *(const float4*)&X[(size_t)(n0+row)*K + k0 + j4];
      Xt[(j4+0)*132 + row] = xv.x;
      Xt[(j4+1)*132 + row] = xv.y;
      Xt[(j4+2)*132 + row] = xv.z;
      Xt[(j4+3)*132 + row] = xv.w;
    }
    __syncthreads();
    for (int k = 0; k < 64; k++){
      float4 a0 = *(const float4*)&Wt[k*132 + 4*tx];
      float4 a1 = *(const float4*)&Wt[k*132 + 64 + 4*tx];
      float4 x0 = *(const float4*)&Xt[k*132 + 4*ty];
      float4 x1 = *(const float4*)&Xt[k*132 + 64 + 4*ty];
      float am[8] = {a0.x,a0.y,a0.z,a0.w,a1.x,a1.y,a1.z,a1.w};
      float xn[8] = {x0.x,x0.y,x0.z,x0.w,x1.x,x1.y,x1.z,x1.w};
      #pragma unroll
      for (int mi = 0; mi < 8; mi++)
        #pragma unroll
        for (int ni = 0; ni < 8; ni++)
          acc[mi][ni] += am[mi]*xn[ni];
    }
    __syncthreads();
  }

  float bvv[8];
  #pragma unroll
  for (int mi = 0; mi < 8; mi++){
    int m = m0 + ((mi < 4) ? (4*tx + mi) : (64 + 4*tx + mi - 4));
    float bb = b1[m];
    if (b2) bb += b2[m];
    bvv[mi] = bb;
  }
  #pragma unroll
  for (int ni = 0; ni < 8; ni++){
    int n = n0 + ((ni < 4) ? (4*ty + ni) : (64 + 4*ty + ni - 4));
    float v[8];
    #pragma unroll
    for (int mi = 0; mi < 8; mi++){
      float q = acc[mi][ni] + bvv[mi];
      if (act == 1) q = fmaxf(q, 0.f);
      else if (act == 2) q = 1.0f/(1.0f + expf(-q));
      v[mi] = q;
    }
    *(float4*)&out[(size_t)n*M + m0 + 4*tx]      = make_float4(v[0],v[1],v[2],v[3]);
    *(float4*)&out[(size_t)n*M + m0 + 64 + 4*tx] = make_float4(v[4],v[5],v[6],v[7]);
  }
}

// ---------------- feature extractor conv chain (per sample block). gf row -> conv1+pool -> conv2+pool -> conv3 -> fs
__launch_bounds__(256)
__global__ void k_feconv(const float* __restrict__ gf, const float* __restrict__ c1w,
                         const float* __restrict__ c1b, const float* __restrict__ c2w,
                         const float* __restrict__ c2b, const float* __restrict__ c3w,
                         const float* __restrict__ c3b, float* __restrict__ fs){
  __shared__ float fc[1024];
  __shared__ float p1[16*512];
  __shared__ float p2[32*256];
  __shared__ float w1[48], w2[1536], w3[96], bb1[16], bb2[32];
  const int r = blockIdx.x, tid = threadIdx.x;
  #pragma unroll
  for (int i = 0; i < 4; i++) fc[i*256 + tid] = gf[(size_t)r*1024 + i*256 + tid];
  if (tid < 48) w1[tid] = c1w[tid];
  if (tid < 16) bb1[tid] = c1b[tid];
  for (int i = tid; i < 1536; i += 256) w2[i] = c2w[i];
  if (tid < 32) bb2[tid] = c2b[tid];
  if (tid < 96) w3[tid] = c3w[tid];
  __syncthreads();
  // conv1 (1->16, len 1024) + relu + pool2
  for (int i = 0; i < 32; i++){
    int idx = i*256 + tid;
    int ch = idx >> 9, p = idx & 511;
    float k0 = w1[ch*3], k1 = w1[ch*3+1], k2 = w1[ch*3+2], bias = bb1[ch];
    int q = 2*p;
    float xm1 = (q >= 1) ? fc[q-1] : 0.f;
    float x0 = fc[q];
    float x1 = fc[q+1];
    float x2 = (q+2 < 1024) ? fc[q+2] : 0.f;
    float a0 = bias + k0*xm1 + k1*x0 + k2*x1;
    float a1 = bias + k0*x0 + k1*x1 + k2*x2;
    p1[ch*512 + p] = fmaxf(fmaxf(a0, 0.f), fmaxf(a1, 0.f));
  }
  __syncthreads();
  // conv2 (16->32, len 512) + relu + pool2
  for (int i = 0; i < 32; i++){
    int idx = i*256 + tid;
    int ch = idx >> 8, p = idx & 255;
    float a0 = bb2[ch], a1 = bb2[ch];
    int q = 2*p;
    #pragma unroll
    for (int ci = 0; ci < 16; ci++){
      const float* wp = &w2[(ch*16+ci)*3];
      const float* ip = &p1[ci*512];
      float xm1 = (q >= 1) ? ip[q-1] : 0.f;
      float x0 = ip[q];
      float x1 = ip[q+1];
      float x2 = (q+2 < 512) ? ip[q+2] : 0.f;
      a0 += wp[0]*xm1 + wp[1]*x0 + wp[2]*x1;
      a1 += wp[0]*x0  + wp[1]*x1 + wp[2]*x2;
    }
    p2[ch*256 + p] = fmaxf(fmaxf(a0, 0.f), fmaxf(a1, 0.f));
  }
  __syncthreads();
  // conv3 (32->1, len 256), no relu
  if (tid < 256){
    float a = c3b[0];
    const int l = tid;
    #pragma unroll
    for (int ci = 0; ci < 32; ci++){
      const float* wp = &w3[ci*3];
      const float* ip = &p2[ci*256];
      float xm1 = (l >= 1) ? ip[l-1] : 0.f;
      float x0 = ip[l];
      float x2 = (l+1 < 256) ? ip[l+1] : 0.f;
      a += wp[0]*xm1 + wp[1]*x0 + wp[2]*x2;
    }
    fs[(size_t)r*256 + l] = a;
  }
}

// ---------------- Wv_eff[g][j] = sum_d Wv[g*256+d][j]*Wao[d]; bve[g] = sum_d bv[g*256+d]*Wao[d]
__launch_bounds__(256)
__global__ void k_wveff(const float* __restrict__ Wv, const float* __restrict__ bvq,
                        const float* __restrict__ Wao, float* __restrict__ wve,
                        float* __restrict__ bve){
  __shared__ float wa[256];
  const int g = blockIdx.x, tid = threadIdx.x;
  wa[tid] = Wao[tid];
  __syncthreads();
  float acc = 0.f;
  for (int d = 0; d < 256; d++)
    acc += Wv[((size_t)(g*256 + d))*256 + tid] * wa[d];
  wve[g*256 + tid] = acc;
  if (tid == 0){
    float s = 0.f;
    for (int d = 0; d < 256; d++) s += bvq[g*256 + d]*wa[d];
    bve[g] = s;
  }
}

// ---------------- per-step S1: gates -> c, og ; also y_{t-1}
__launch_bounds__(256)
__global__ void k_s1(const float* __restrict__ gx, const float* __restrict__ Wh,
                     const float* __restrict__ Wout, const float* __restrict__ bout,
                     float* __restrict__ h, float* __restrict__ c, float* __restrict__ og,
                     float* __restrict__ y, int t){
  __shared__ float hl[256];
  __shared__ float gp[4][64];
  const int blk = blockIdx.x, tid = threadIdx.x;
  if (blk < 32){
    const int b = blk >> 2, ot = (blk & 3) * 64;
    hl[tid] = h[b*256 + tid];
    __syncthreads();
    const int gate = tid >> 6, oo = tid & 63;
    const int row = gate*256 + ot + oo;
    float acc = gx[(size_t)(t*8 + b)*1024 + row];
    const float4* wr = (const float4*)&Wh[(size_t)row*256];
    const float4* hp = (const float4*)hl;
    #pragma unroll 8
    for (int j = 0; j < 64; j++){
      float4 w = wr[j]; float4 hv = hp[j];
      acc += w.x*hv.x + w.y*hv.y + w.z*hv.z + w.w*hv.w;
    }
    gp[gate][oo] = acc;
    __syncthreads();
    if (tid < 64){
      const int o = ot + tid, ci = b*256 + o;
      float ig = sigmf(gp[0][tid]);
      float fg = sigmf(gp[1][tid]);
      float gg = tanhf(gp[2][tid]);
      float ov = sigmf(gp[3][tid]);
      float cn = fg * c[ci] + ig * gg;
      c[ci] = cn;
      og[ci] = ov;
    }
  } else if (t > 0 && tid < 80){
    const int b = tid / 10, cc = tid - b*10;
    float acc = bout[cc];
    const float* hr = &h[b*256];
    const float* wr = &Wout[cc*256];
    for (int i = 0; i < 256; i++) acc += hr[i]*wr[i];
    y[b*640 + cc*64 + (t-1)] = acc;
  }
}

// ---------------- per-step S2: Kt[b][d*256+g] = Wk[g*256+d][:] . c[b][:] + bk ; also vw = og @ Wv_eff^T + bve
__launch_bounds__(256)
__global__ void k_s2(const float* __restrict__ Wk, const float* __restrict__ bk,
                     const float* __restrict__ c, const float* __restrict__ og,
                     const float* __restrict__ wve, const float* __restrict__ bve,
                     float* __restrict__ Kt, float* __restrict__ vw){
  __shared__ float cl[8*260];
  const int blk = blockIdx.x, tid = threadIdx.x;
  #pragma unroll
  for (int i = 0; i < 8; i++){
    int f = i*256 + tid;
    cl[(f >> 8)*260 + (f & 255)] = c[f];
  }
  __syncthreads();
  // vw: 8 outputs per block via first wave
  if (tid < 64){
    const int bp = blk >> 5, g0 = (blk & 31)*8;
    const int oi = tid >> 3, part = tid & 7;
    const int gg = g0 + oi;
    const float4* wv4 = (const float4*)&wve[gg*256];
    const float4* o4 = (const float4*)&og[bp*256];
    float s = 0.f;
    #pragma unroll
    for (int j = part*8; j < part*8 + 8; j++){
      float4 w = wv4[j], o = o4[j];
      s += w.x*o.x + w.y*o.y + w.z*o.z + w.w*o.w;
    }
    s += __shfl_xor(s, 1);
    s += __shfl_xor(s, 2);
    s += __shfl_xor(s, 4);
    if (part == 0) vw[bp*256 + gg] = s + bve[gg];
  }
  const int g = (blk & 3)*64 + (tid & 63);
  const int d = (blk >> 2)*4 + (tid >> 6);
  const int row = g*256 + d;
  float acc[8];
  const float bkv = bk[row];
  #pragma unroll
  for (int bb = 0; bb < 8; bb++) acc[bb] = bkv;
  const float4* wr = (const float4*)&Wk[(size_t)row*256];
  for (int j = 0; j < 64; j++){
    float4 w = wr[j];
    #pragma unroll
    for (int bb = 0; bb < 8; bb++){
      float4 cv = *(const float4*)&cl[bb*260 + j*4];
      acc[bb] += w.x*cv.x + w.y*cv.y + w.z*cv.z + w.w*cv.w;
    }
  }
  #pragma unroll
  for (int bb = 0; bb < 8; bb++)
    Kt[bb*65536 + d*256 + g] = acc[bb];
}

// ---------------- per-step S3: logits = Q_t K^T * scale, softmax over g, h = attn.vw + bao
__launch_bounds__(256)
__global__ void k_s3(const float* __restrict__ Q, const float* __restrict__ Kt,
                     const float* __restrict__ vw, const float* __restrict__ bao,
                     float* __restrict__ h, int t){
  __shared__ float Kl[64*260];
  __shared__ float Ql[256*10];
  __shared__ float ll[8*260];
  __shared__ float vwl[256];
  const int blk = blockIdx.x, tid = threadIdx.x;
  const int b = blk >> 5, h0 = (blk & 31)*8;
  vwl[tid] = vw[b*256 + tid];
  {
    const float* Qb = &Q[(size_t)(t*8 + b)*65536 + (size_t)h0*256];
    #pragma unroll
    for (int i = 0; i < 2; i++){
      int f4 = i*256 + tid;
      int hh = f4 >> 6, d4 = (f4 & 63)*4;
      float4 q = *(const float4*)&Qb[hh*256 + d4];
      Ql[(d4+0)*10 + hh] = q.x;
      Ql[(d4+1)*10 + hh] = q.y;
      Ql[(d4+2)*10 + hh] = q.z;
      Ql[(d4+3)*10 + hh] = q.w;
    }
  }
  const int w = tid >> 6, lane = tid & 63;
  const int hg = lane >> 4, gq = lane & 15;
  const int gb = w*64 + gq*4;
  float acc[2][4] = {{0,0,0,0},{0,0,0,0}};
  const float* Kb = &Kt[(size_t)b*65536];
  for (int dt = 0; dt < 4; dt++){
    __syncthreads();
    #pragma unroll
    for (int i = 0; i < 16; i++){
      int f4 = i*256 + tid;
      int dl = f4 >> 6, g4 = (f4 & 63)*4;
      *(float4*)&Kl[dl*260 + g4] = *(const float4*)&Kb[(dt*64 + dl)*256 + g4];
    }
    __syncthreads();
    for (int dl = 0; dl < 64; dl++){
      float2 qv = *(const float2*)&Ql[(dt*64 + dl)*10 + hg*2];
      float4 kv = *(const float4*)&Kl[dl*260 + gb];
      acc[0][0] += qv.x*kv.x; acc[0][1] += qv.x*kv.y; acc[0][2] += qv.x*kv.z; acc[0][3] += qv.x*kv.w;
      acc[1][0] += qv.y*kv.x; acc[1][1] += qv.y*kv.y; acc[1][2] += qv.y*kv.z; acc[1][3] += qv.y*kv.w;
    }
  }
  const float scale = 0.0625f;
  #pragma unroll
  for (int a = 0; a < 2; a++)
    #pragma unroll
    for (int i = 0; i < 4; i++)
      ll[(hg*2 + a)*260 + gb + i] = acc[a][i]*scale;
  __syncthreads();
  const int hr = tid >> 5, ln = tid & 31;
  float lv[8];
  float m = -3.0e38f;
  #pragma unroll
  for (int i = 0; i < 8; i++){
    lv[i] = ll[hr*260 + ln + i*32];
    m = fmaxf(m, lv[i]);
  }
  #pragma unroll
  for (int s = 16; s >= 1; s >>= 1) m = fmaxf(m, __shfl_xor(m, s));
  float den = 0.f, num = 0.f;
  #pragma unroll
  for (int i = 0; i < 8; i++){
    float p = expf(lv[i] - m);
    den += p;
    num += p * vwl[ln + i*32];
  }
  #pragma unroll
  for (int s = 16; s >= 1; s >>= 1){
    den += __shfl_xor(den, s);
    num += __shfl_xor(num, s);
  }
  if (ln == 0) h[b*256 + h0 + hr] = num/den + bao[0];
}

// ---------------- final y_63
__launch_bounds__(128)
__global__ void k_final(const float* __restrict__ h, const float* __restrict__ Wout,
                        const float* __restrict__ bout, float* __restrict__ y){
  const int tid = threadIdx.x;
  if (tid < 80){
    const int b = tid / 10, cc = tid - b*10;
    float acc = bout[cc];
    const float* hr = &h[b*256];
    const float* wr = &Wout[cc*256];
    for (int i = 0; i < 256; i++) acc += hr[i]*wr[i];
    y[b*640 + cc*64 + 63] = acc;
  }
}

extern "C" void kernel_launch(void* const* d_in, const int* in_sizes, int n_in,
                              void* d_out, int out_size, void* d_ws, size_t ws_size,
                              hipStream_t stream){
  (void)in_sizes; (void)n_in; (void)out_size; (void)ws_size;
  const float* x      = (const float*)d_in[0];
  const float* w_init = (const float*)d_in[1];
  const float* b_init = (const float*)d_in[2];
  const float* c1w    = (const float*)d_in[3];
  const float* c1b    = (const float*)d_in[4];
  const float* c2w    = (const float*)d_in[5];
  const float* c2b    = (const float*)d_in[6];
  const float* c3w    = (const float*)d_in[7];
  const float* c3b    = (const float*)d_in[8];
  const float* Wx     = (const float*)d_in[9];
  const float* bx     = (const float*)d_in[10];
  const float* Wh     = (const float*)d_in[11];
  const float* bh     = (const float*)d_in[12];
  const float* Wxo    = (const float*)d_in[13];
  const float* bxo    = (const float*)d_in[14];
  const float* Wq     = (const float*)d_in[15];
  const float* bq     = (const float*)d_in[16];
  const float* Wk     = (const float*)d_in[17];
  const float* bk     = (const float*)d_in[18];
  const float* Wv     = (const float*)d_in[19];
  const float* bv     = (const float*)d_in[20];
  const float* Wao    = (const float*)d_in[21];
  const float* bao    = (const float*)d_in[22];
  const float* Wout   = (const float*)d_in[23];
  const float* bout   = (const float*)d_in[24];
  float* y  = (float*)d_out;
  float* ws = (float*)d_ws;

  float* xin = ws + WS_XIN;
  float* gf  = ws + WS_GF;
  float* fs  = ws + WS_FS;
  float* xo  = ws + WS_XO;
  float* gxp = ws + WS_GX;
  float* Qp  = ws + WS_Q;
  float* wve = ws + WS_WVE;
  float* bve = ws + WS_BVE;
  float* Ktp = ws + WS_KT;
  float* hp  = ws + WS_H;
  float* cp  = ws + WS_C;
  float* ogp = ws + WS_OG;
  float* vwp = ws + WS_VW;

  k_init<<<256, 256, 0, stream>>>(x, ws);
  // FC: gf = relu(xin @ w_init^T + b_init)   M=1024 K=128
  k_gemm_nt<<<dim3(8, 4), 256, 0, stream>>>(w_init, xin, b_init, nullptr, gf, 1024, 128, 1);
  // conv chain -> fs
  k_feconv<<<512, 256, 0, stream>>>(gf, c1w, c1b, c2w, c2b, c3w, c3b, fs);
  // x_o = sigmoid(fs @ Wxo^T + bxo)          M=256 K=256
  k_gemm_nt<<<dim3(2, 4), 256, 0, stream>>>(Wxo, fs, bxo, nullptr, xo, 256, 256, 2);
  // gx = fs @ Wx^T + bx + bh                 M=1024 K=256
  k_gemm_nt<<<dim3(8, 4), 256, 0, stream>>>(Wx, fs, bx, bh, gxp, 1024, 256, 0);
  // Wv_eff, bv_eff
  k_wveff<<<256, 256, 0, stream>>>(Wv, bv, Wao, wve, bve);
  // Q = xo @ Wq^T + bq                       M=65536 K=256
  k_gemm_nt<<<dim3(512, 4), 256, 0, stream>>>(Wq, xo, bq, nullptr, Qp, 65536, 256, 0);

  for (int t = 0; t < 64; t++){
    k_s1<<<33, 256, 0, stream>>>(gxp, Wh, Wout, bout, hp, cp, ogp, y, t);
    k_s2<<<256, 256, 0, stream>>>(Wk, bk, cp, ogp, wve, bve, Ktp, vwp);
    k_s3<<<256, 256, 0, stream>>>(Qp, Ktp, vwp, bao, hp, t);
  }
  k_final<<<1, 128, 0, stream>>>(hp, Wout, bout, y);
}

// Round 2
// 3370.681 us; speedup vs baseline: 1.0261x; 1.0261x over previous
//
#include <hip/hip_runtime.h>
#include <math.h>

// Workspace layout (float offsets)
#define WS_XIN   0L          // [512][128]
#define WS_GF    65536L      // [512][1024]
#define WS_FS    589824L     // [512][256]
#define WS_XO    720896L     // [512][256]
#define WS_GX    851968L     // [512][1024]
#define WS_Q     1376256L    // [512][65536]
#define WS_WVE   34930688L   // [256][256]
#define WS_BVE   34996224L   // [256]
#define WS_KT    34996480L   // [8][65536]  (Kt[b][d*256+g])
#define WS_HH    35520768L   // [65][2048]  h history, slot 0 = h_{-1} = 0
#define WS_C     35653888L   // [8][256]
#define WS_OG    35655936L   // [8][256]
#define WS_VW    35657984L   // [8][256]
// total 35660032 floats = 142.6 MB

__device__ __forceinline__ float sigmf(float x){ return 1.0f/(1.0f + expf(-x)); }

// ---------------- init: zero h_{-1},c and build xin[r][m] = x[b][m][t], r = t*8+b
__launch_bounds__(256)
__global__ void k_init(const float* __restrict__ x, float* __restrict__ ws){
  int i = blockIdx.x*256 + threadIdx.x;   // 65536 threads
  int r = i >> 7, m = i & 127;
  int t = r >> 3, b = r & 7;
  ws[WS_XIN + i] = x[b*8192 + m*64 + t];
  if (i < 2048){ ws[WS_HH + i] = 0.f; ws[WS_C + i] = 0.f; }
}

// ---------------- generic GEMM: out[n][m] = act( sum_k W[m][k]*X[n][k] + b1[m] (+b2[m]) )
__launch_bounds__(256)
__global__ void k_gemm_nt(const float* __restrict__ W, const float* __restrict__ X,
                          const float* __restrict__ b1, const float* __restrict__ b2,
                          float* __restrict__ out, int M, int K, int act){
  __shared__ float Wt[64*132];
  __shared__ float Xt[64*132];
  const int tid = threadIdx.x;
  const int tx = tid & 15, ty = tid >> 4;
  const int m0 = blockIdx.x * 128, n0 = blockIdx.y * 128;
  float acc[8][8];
  #pragma unroll
  for (int i = 0; i < 8; i++)
    #pragma unroll
    for (int j = 0; j < 8; j++) acc[i][j] = 0.f;

  for (int k0 = 0; k0 < K; k0 += 64){
    #pragma unroll
    for (int i = 0; i < 8; i++){
      int f4 = i*256 + tid;
      int row = f4 >> 4;
      int j4 = (tid & 15) * 4;
      float4 w = *(const float4*)&W[(size_t)(m0+row)*K + k0 + j4];
      Wt[(j4+0)*132 + row] = w.x;
      Wt[(j4+1)*132 + row] = w.y;
      Wt[(j4+2)*132 + row] = w.z;
      Wt[(j4+3)*132 + row] = w.w;
      float4 xv = *(const float4*)&X[(size_t)(n0+row)*K + k0 + j4];
      Xt[(j4+0)*132 + row] = xv.x;
      Xt[(j4+1)*132 + row] = xv.y;
      Xt[(j4+2)*132 + row] = xv.z;
      Xt[(j4+3)*132 + row] = xv.w;
    }
    __syncthreads();
    for (int k = 0; k < 64; k++){
      float4 a0 = *(const float4*)&Wt[k*132 + 4*tx];
      float4 a1 = *(const float4*)&Wt[k*132 + 64 + 4*tx];
      float4 x0 = *(const float4*)&Xt[k*132 + 4*ty];
      float4 x1 = *(const float4*)&Xt[k*132 + 64 + 4*ty];
      float am[8] = {a0.x,a0.y,a0.z,a0.w,a1.x,a1.y,a1.z,a1.w};
      float xn[8] = {x0.x,x0.y,x0.z,x0.w,x1.x,x1.y,x1.z,x1.w};
      #pragma unroll
      for (int mi = 0; mi < 8; mi++)
        #pragma unroll
        for (int ni = 0; ni < 8; ni++)
          acc[mi][ni] += am[mi]*xn[ni];
    }
    __syncthreads();
  }

  float bvv[8];
  #pragma unroll
  for (int mi = 0; mi < 8; mi++){
    int m = m0 + ((mi < 4) ? (4*tx + mi) : (64 + 4*tx + mi - 4));
    float bb = b1[m];
    if (b2) bb += b2[m];
    bvv[mi] = bb;
  }
  #pragma unroll
  for (int ni = 0; ni < 8; ni++){
    int n = n0 + ((ni < 4) ? (4*ty + ni) : (64 + 4*ty + ni - 4));
    float v[8];
    #pragma unroll
    for (int mi = 0; mi < 8; mi++){
      float q = acc[mi][ni] + bvv[mi];
      if (act == 1) q = fmaxf(q, 0.f);
      else if (act == 2) q = 1.0f/(1.0f + expf(-q));
      v[mi] = q;
    }
    *(float4*)&out[(size_t)n*M + m0 + 4*tx]      = make_float4(v[0],v[1],v[2],v[3]);
    *(float4*)&out[(size_t)n*M + m0 + 64 + 4*tx] = make_float4(v[4],v[5],v[6],v[7]);
  }
}

// ---------------- feature extractor conv chain
__launch_bounds__(256)
__global__ void k_feconv(const float* __restrict__ gf, const float* __restrict__ c1w,
                         const float* __restrict__ c1b, const float* __restrict__ c2w,
                         const float* __restrict__ c2b, const float* __restrict__ c3w,
                         const float* __restrict__ c3b, float* __restrict__ fs){
  __shared__ float fc[1024];
  __shared__ float p1[16*512];
  __shared__ float p2[32*256];
  __shared__ float w1[48], w2[1536], w3[96], bb1[16], bb2[32];
  const int r = blockIdx.x, tid = threadIdx.x;
  #pragma unroll
  for (int i = 0; i < 4; i++) fc[i*256 + tid] = gf[(size_t)r*1024 + i*256 + tid];
  if (tid < 48) w1[tid] = c1w[tid];
  if (tid < 16) bb1[tid] = c1b[tid];
  for (int i = tid; i < 1536; i += 256) w2[i] = c2w[i];
  if (tid < 32) bb2[tid] = c2b[tid];
  if (tid < 96) w3[tid] = c3w[tid];
  __syncthreads();
  for (int i = 0; i < 32; i++){
    int idx = i*256 + tid;
    int ch = idx >> 9, p = idx & 511;
    float k0 = w1[ch*3], k1 = w1[ch*3+1], k2 = w1[ch*3+2], bias = bb1[ch];
    int q = 2*p;
    float xm1 = (q >= 1) ? fc[q-1] : 0.f;
    float x0 = fc[q];
    float x1 = fc[q+1];
    float x2 = (q+2 < 1024) ? fc[q+2] : 0.f;
    float a0 = bias + k0*xm1 + k1*x0 + k2*x1;
    float a1 = bias + k0*x0 + k1*x1 + k2*x2;
    p1[ch*512 + p] = fmaxf(fmaxf(a0, 0.f), fmaxf(a1, 0.f));
  }
  __syncthreads();
  for (int i = 0; i < 32; i++){
    int idx = i*256 + tid;
    int ch = idx >> 8, p = idx & 255;
    float a0 = bb2[ch], a1 = bb2[ch];
    int q = 2*p;
    #pragma unroll
    for (int ci = 0; ci < 16; ci++){
      const float* wp = &w2[(ch*16+ci)*3];
      const float* ip = &p1[ci*512];
      float xm1 = (q >= 1) ? ip[q-1] : 0.f;
      float x0 = ip[q];
      float x1 = ip[q+1];
      float x2 = (q+2 < 512) ? ip[q+2] : 0.f;
      a0 += wp[0]*xm1 + wp[1]*x0 + wp[2]*x1;
      a1 += wp[0]*x0  + wp[1]*x1 + wp[2]*x2;
    }
    p2[ch*256 + p] = fmaxf(fmaxf(a0, 0.f), fmaxf(a1, 0.f));
  }
  __syncthreads();
  if (tid < 256){
    float a = c3b[0];
    const int l = tid;
    #pragma unroll
    for (int ci = 0; ci < 32; ci++){
      const float* wp = &w3[ci*3];
      const float* ip = &p2[ci*256];
      float xm1 = (l >= 1) ? ip[l-1] : 0.f;
      float x0 = ip[l];
      float x2 = (l+1 < 256) ? ip[l+1] : 0.f;
      a += wp[0]*xm1 + wp[1]*x0 + wp[2]*x2;
    }
    fs[(size_t)r*256 + l] = a;
  }
}

// ---------------- Wv_eff[g][j] = sum_d Wv[g*256+d][j]*Wao[d]; bve[g] = sum_d bv[g*256+d]*Wao[d]
__launch_bounds__(256)
__global__ void k_wveff(const float* __restrict__ Wv, const float* __restrict__ bvq,
                        const float* __restrict__ Wao, float* __restrict__ wve,
                        float* __restrict__ bve){
  __shared__ float wa[256];
  const int g = blockIdx.x, tid = threadIdx.x;
  wa[tid] = Wao[tid];
  __syncthreads();
  float acc = 0.f;
  for (int d = 0; d < 256; d++)
    acc += Wv[((size_t)(g*256 + d))*256 + tid] * wa[d];
  wve[g*256 + tid] = acc;
  if (tid == 0){
    float s = 0.f;
    for (int d = 0; d < 256; d++) s += bvq[g*256 + d]*wa[d];
    bve[g] = s;
  }
}

// ---------------- per-step S1: gates -> c, og.  8192 dots x 8 threads, grid 256.
__launch_bounds__(256)
__global__ void k_s1(const float* __restrict__ gx, const float* __restrict__ Wh,
                     const float* __restrict__ hprev, float* __restrict__ c,
                     float* __restrict__ og, int t){
  __shared__ float hl[256];
  __shared__ float gl[32];
  const int blk = blockIdx.x, tid = threadIdx.x;
  const int b = blk >> 5;                         // 32 blocks per batch
  hl[tid] = hprev[b*256 + tid];
  __syncthreads();
  const int j = tid >> 3;                         // local dot index 0..31
  const int part = tid & 7;
  const int Rl = blk*32 + j;                      // [0,8192): b*1024 + o*4 + gate
  const int rr = Rl & 1023;
  const int o = rr >> 2, gate = rr & 3;
  const int row = gate*256 + o;
  const float4* wr = (const float4*)&Wh[(size_t)row*256 + part*32];
  const float4* hv = (const float4*)&hl[part*32];
  float acc = 0.f;
  #pragma unroll
  for (int u = 0; u < 8; u++){
    float4 w = wr[u], h4 = hv[u];
    acc += w.x*h4.x + w.y*h4.y + w.z*h4.z + w.w*h4.w;
  }
  acc += __shfl_xor(acc, 1);
  acc += __shfl_xor(acc, 2);
  acc += __shfl_xor(acc, 4);
  if (part == 0) gl[j] = acc + gx[(size_t)(t*8 + b)*1024 + row];
  __syncthreads();
  if (tid < 8){
    const int o_ = ((blk & 31)*8) + tid;
    const int ci = b*256 + o_;
    float ig = sigmf(gl[tid*4 + 0]);
    float fg = sigmf(gl[tid*4 + 1]);
    float gg = tanhf(gl[tid*4 + 2]);
    float ov = sigmf(gl[tid*4 + 3]);
    c[ci] = fg*c[ci] + ig*gg;
    og[ci] = ov;
  }
}

// ---------------- per-step S2: Kt[b][d*256+g] = Wk[g*256+d][:] . c[b][:] + bk ; blocks>=2048: vw
__launch_bounds__(256)
__global__ void k_s2(const float* __restrict__ Wk, const float* __restrict__ bk,
                     const float* __restrict__ c, const float* __restrict__ og,
                     const float* __restrict__ wve, const float* __restrict__ bve,
                     float* __restrict__ Kt, float* __restrict__ vw){
  const int blk = blockIdx.x, tid = threadIdx.x;
  if (blk >= 2048){
    __shared__ float ogl[256];
    const int b = blk - 2048;
    ogl[tid] = og[b*256 + tid];
    __syncthreads();
    const float4* o4 = (const float4*)ogl;
    const float4* w4 = (const float4*)&wve[tid*256];
    float s = 0.f;
    #pragma unroll 8
    for (int u = 0; u < 64; u++){
      float4 w = w4[u], o = o4[u];
      s += w.x*o.x + w.y*o.y + w.z*o.z + w.w*o.w;
    }
    vw[b*256 + tid] = s + bve[tid];
    return;
  }
  __shared__ float cl[8*260];
  #pragma unroll
  for (int i = 0; i < 8; i++){
    int f = i*256 + tid;
    cl[(f >> 8)*260 + (f & 255)] = c[f];
  }
  __syncthreads();
  const int j = tid >> 3, part = tid & 7;
  const int R = blk*32 + j;                  // R = d*256 + g  (d fixed per block)
  const int d = R >> 8, g = R & 255;
  const int row = g*256 + d;                 // Wk row index
  const float4* wr = (const float4*)&Wk[(size_t)row*256 + part*32];
  float acc[8];
  #pragma unroll
  for (int bb = 0; bb < 8; bb++) acc[bb] = 0.f;
  #pragma unroll
  for (int u = 0; u < 8; u++){
    float4 w = wr[u];
    #pragma unroll
    for (int bb = 0; bb < 8; bb++){
      float4 cv = *(const float4*)&cl[bb*260 + part*32 + u*4];
      acc[bb] += w.x*cv.x + w.y*cv.y + w.z*cv.z + w.w*cv.w;
    }
  }
  #pragma unroll
  for (int bb = 0; bb < 8; bb++){
    acc[bb] += __shfl_xor(acc[bb], 1);
    acc[bb] += __shfl_xor(acc[bb], 2);
    acc[bb] += __shfl_xor(acc[bb], 4);
  }
  const float bkv = bk[row];
  Kt[part*65536 + d*256 + g] = acc[part] + bkv;
}

// ---------------- per-step S3: logits=Q K^T*scale, softmax, h = attn.vw + bao -> hH[t+1]
__launch_bounds__(256)
__global__ void k_s3(const float* __restrict__ Q, const float* __restrict__ Kt,
                     const float* __restrict__ vw, const float* __restrict__ bao,
                     float* __restrict__ hout, int t){
  __shared__ float Ql[256*9];       // [d][hh] pad 9
  __shared__ float KL[32*260];      // [dl][g] pad 260
  __shared__ float vwl[256];
  __shared__ float wm[4][8], wd[4][8], wn[4][8];
  const int blk = blockIdx.x, tid = threadIdx.x;
  const int b = blk >> 5, h0 = (blk & 31)*8;
  vwl[tid] = vw[b*256 + tid];
  const float* Qb = &Q[(size_t)(t*8 + b)*65536 + (size_t)h0*256];
  #pragma unroll
  for (int i = 0; i < 8; i++){
    int f = i*256 + tid;               // hh = f>>8, d = f&255
    Ql[(f & 255)*9 + (f >> 8)] = Qb[(f >> 8)*256 + (f & 255)];
  }
  const int md = tid & 3, lq = tid >> 2;   // lq in [0,64): g quad; md: d split (in-wave)
  float acc[8][4];
  #pragma unroll
  for (int hh = 0; hh < 8; hh++)
    #pragma unroll
    for (int q = 0; q < 4; q++) acc[hh][q] = 0.f;
  const float* Kb = &Kt[(size_t)b*65536];
  for (int dt = 0; dt < 8; dt++){
    __syncthreads();
    #pragma unroll
    for (int i2 = 0; i2 < 8; i2++){
      int f = i2*256 + tid;
      int dl = f >> 6, gc = (f & 63)*4;
      *(float4*)&KL[dl*260 + gc] = *(const float4*)&Kb[(dt*32 + dl)*256 + gc];
    }
    __syncthreads();
    #pragma unroll
    for (int dlj = 0; dlj < 8; dlj++){
      const int dl = md*8 + dlj;
      const int d = dt*32 + dl;
      float4 kv = *(const float4*)&KL[dl*260 + lq*4];
      const float* qp = &Ql[d*9];
      #pragma unroll
      for (int hh = 0; hh < 8; hh++){
        float qv = qp[hh];
        acc[hh][0] += qv*kv.x; acc[hh][1] += qv*kv.y;
        acc[hh][2] += qv*kv.z; acc[hh][3] += qv*kv.w;
      }
    }
  }
  // reduce over md (lanes xor 1,2), scale
  #pragma unroll
  for (int hh = 0; hh < 8; hh++)
    #pragma unroll
    for (int q = 0; q < 4; q++){
      float a = acc[hh][q];
      a += __shfl_xor(a, 1);
      a += __shfl_xor(a, 2);
      acc[hh][q] = a * 0.0625f;
    }
  // per-wave softmax partials over this wave's 16 lq (g = lq*4+q)
  float4 vv = *(const float4*)&vwl[lq*4];
  const int w = tid >> 6;
  #pragma unroll
  for (int hh = 0; hh < 8; hh++){
    float mx = fmaxf(fmaxf(acc[hh][0], acc[hh][1]), fmaxf(acc[hh][2], acc[hh][3]));
    #pragma unroll
    for (int s = 4; s <= 32; s <<= 1) mx = fmaxf(mx, __shfl_xor(mx, s));
    float p0 = expf(acc[hh][0] - mx);
    float p1 = expf(acc[hh][1] - mx);
    float p2 = expf(acc[hh][2] - mx);
    float p3 = expf(acc[hh][3] - mx);
    float den = p0 + p1 + p2 + p3;
    float num = p0*vv.x + p1*vv.y + p2*vv.z + p3*vv.w;
    #pragma unroll
    for (int s = 4; s <= 32; s <<= 1){ den += __shfl_xor(den, s); num += __shfl_xor(num, s); }
    if ((tid & 63) == 0){ wm[w][hh] = mx; wd[w][hh] = den; wn[w][hh] = num; }
  }
  __syncthreads();
  if (tid < 8){
    float m = fmaxf(fmaxf(wm[0][tid], wm[1][tid]), fmaxf(wm[2][tid], wm[3][tid]));
    float D = 0.f, N = 0.f;
    #pragma unroll
    for (int ww = 0; ww < 4; ww++){
      float e = expf(wm[ww][tid] - m);
      D += wd[ww][tid]*e;
      N += wn[ww][tid]*e;
    }
    hout[b*256 + h0 + tid] = N/D + bao[0];
  }
}

// ---------------- final y: y[b][cls][t] = hH[t+1][b] . Wout[cls] + bout
__launch_bounds__(128)
__global__ void k_y(const float* __restrict__ hH, const float* __restrict__ Wout,
                    const float* __restrict__ bout, float* __restrict__ y){
  const int t = blockIdx.x, tid = threadIdx.x;
  if (tid < 80){
    const int b = tid/10, cc = tid - b*10;
    const float4* hr = (const float4*)&hH[(size_t)(t+1)*2048 + b*256];
    const float4* wr = (const float4*)&Wout[cc*256];
    float acc = 0.f;
    #pragma unroll 8
    for (int u = 0; u < 64; u++){
      float4 h4 = hr[u], w4 = wr[u];
      acc += h4.x*w4.x + h4.y*w4.y + h4.z*w4.z + h4.w*w4.w;
    }
    y[b*640 + cc*64 + t] = acc + bout[cc];
  }
}

extern "C" void kernel_launch(void* const* d_in, const int* in_sizes, int n_in,
                              void* d_out, int out_size, void* d_ws, size_t ws_size,
                              hipStream_t stream){
  (void)in_sizes; (void)n_in; (void)out_size; (void)ws_size;
  const float* x      = (const float*)d_in[0];
  const float* w_init = (const float*)d_in[1];
  const float* b_init = (const float*)d_in[2];
  const float* c1w    = (const float*)d_in[3];
  const float* c1b    = (const float*)d_in[4];
  const float* c2w    = (const float*)d_in[5];
  const float* c2b    = (const float*)d_in[6];
  const float* c3w    = (const float*)d_in[7];
  const float* c3b    = (const float*)d_in[8];
  const float* Wx     = (const float*)d_in[9];
  const float* bx     = (const float*)d_in[10];
  const float* Wh     = (const float*)d_in[11];
  const float* bh     = (const float*)d_in[12];
  const float* Wxo    = (const float*)d_in[13];
  const float* bxo    = (const float*)d_in[14];
  const float* Wq     = (const float*)d_in[15];
  const float* bq     = (const float*)d_in[16];
  const float* Wk     = (const float*)d_in[17];
  const float* bk     = (const float*)d_in[18];
  const float* Wv     = (const float*)d_in[19];
  const float* bv     = (const float*)d_in[20];
  const float* Wao    = (const float*)d_in[21];
  const float* bao    = (const float*)d_in[22];
  const float* Wout   = (const float*)d_in[23];
  const float* bout   = (const float*)d_in[24];
  float* y  = (float*)d_out;
  float* ws = (float*)d_ws;

  float* xin = ws + WS_XIN;
  float* gf  = ws + WS_GF;
  float* fs  = ws + WS_FS;
  float* xo  = ws + WS_XO;
  float* gxp = ws + WS_GX;
  float* Qp  = ws + WS_Q;
  float* wve = ws + WS_WVE;
  float* bve = ws + WS_BVE;
  float* Ktp = ws + WS_KT;
  float* hH  = ws + WS_HH;
  float* cp  = ws + WS_C;
  float* ogp = ws + WS_OG;
  float* vwp = ws + WS_VW;

  k_init<<<256, 256, 0, stream>>>(x, ws);
  k_gemm_nt<<<dim3(8, 4), 256, 0, stream>>>(w_init, xin, b_init, nullptr, gf, 1024, 128, 1);
  k_feconv<<<512, 256, 0, stream>>>(gf, c1w, c1b, c2w, c2b, c3w, c3b, fs);
  k_gemm_nt<<<dim3(2, 4), 256, 0, stream>>>(Wxo, fs, bxo, nullptr, xo, 256, 256, 2);
  k_gemm_nt<<<dim3(8, 4), 256, 0, stream>>>(Wx, fs, bx, bh, gxp, 1024, 256, 0);
  k_wveff<<<256, 256, 0, stream>>>(Wv, bv, Wao, wve, bve);
  k_gemm_nt<<<dim3(512, 4), 256, 0, stream>>>(Wq, xo, bq, nullptr, Qp, 65536, 256, 0);

  for (int t = 0; t < 64; t++){
    k_s1<<<256, 256, 0, stream>>>(gxp, Wh, hH + (size_t)t*2048, cp, ogp, t);
    k_s2<<<2056, 256, 0, stream>>>(Wk, bk, cp, ogp, wve, bve, Ktp, vwp);
    k_s3<<<256, 256, 0, stream>>>(Qp, Ktp, vwp, bao, hH + (size_t)(t+1)*2048, t);
  }
  k_y<<<64, 128, 0, stream>>>(hH, Wout, bout, y);
}